// Round 12
// baseline (291.409 us; speedup 1.0000x reference)
//
#include <hip/hip_runtime.h>

typedef unsigned short u16;
typedef __attribute__((ext_vector_type(8))) __bf16 bf16x8;
typedef __attribute__((ext_vector_type(4))) float f32x4;
typedef __attribute__((ext_vector_type(8))) u16 u16x8;
typedef __attribute__((ext_vector_type(4))) u16 u16x4;

__device__ __forceinline__ float bf2f(u16 u) {
  return __builtin_bit_cast(float, ((unsigned)u) << 16);
}
__device__ __forceinline__ u16 f2bf(float f) {
  unsigned x = __builtin_bit_cast(unsigned, f);
  x += 0x7fffu + ((x >> 16) & 1u);
  return (u16)(x >> 16);
}
__device__ __forceinline__ f32x4 cvt4(u16x4 v) {
  return (f32x4){bf2f(v.x), bf2f(v.y), bf2f(v.z), bf2f(v.w)};
}
__device__ __forceinline__ void gload_lds16(const void* g, void* l) {
  __builtin_amdgcn_global_load_lds(
      (const __attribute__((address_space(1))) void*)g,
      (__attribute__((address_space(3))) void*)l, 16, 0, 0);
}

// ---- fused prep: cvtx (x->bf16) | prepw x4 (W->Wt bf16) | rowptr, by block range ----
__global__ void prep_kernel(const float* __restrict__ x, u16* __restrict__ x_bf, int cvtxBlocks,
                            const float* __restrict__ W0, u16* __restrict__ T0,
                            const float* __restrict__ W1, u16* __restrict__ T1,
                            const float* __restrict__ W2, u16* __restrict__ T2,
                            const float* __restrict__ W3, u16* __restrict__ T3,
                            const int* __restrict__ rows, int nE, int* __restrict__ rp, int nN) {
  int b = blockIdx.x;
  if (b < cvtxBlocks) {
    int i = b * 256 + threadIdx.x;
    if (i >= nN * 64) return;
    const float4 v = ((const float4*)x)[i];
    u16x4 o = { f2bf(v.x), f2bf(v.y), f2bf(v.z), f2bf(v.w) };
    ((u16x4*)x_bf)[i] = o;
    return;
  }
  b -= cvtxBlocks;
  if (b < 1280) {
    int i = b * 256 + threadIdx.x;
    const float* W; u16* T; int K, N;
    if (i < 65536)        { W = W0; T = T0; K = 256; N = 256; }
    else if (i < 131072)  { W = W1; T = T1; K = 256; N = 256; i -= 65536; }
    else if (i < 262144)  { W = W2; T = T2; K = 512; N = 256; i -= 131072; }
    else if (i < 327680)  { W = W3; T = T3; K = 512; N = 128; i -= 262144; }
    else return;
    int k = i / N, n = i - k * N;
    T[(size_t)n * K + k] = f2bf(W[i]);
    return;
  }
  b -= 1280;
  int i = b * 256 + threadIdx.x;
  if (i > nN) return;
  int lo = 0, hi = nE;
  while (lo < hi) { int mid = (lo + hi) >> 1; if (rows[mid] < i) lo = mid + 1; else hi = mid; }
  rp[i] = lo;
}

// ---- mega layer kernel: per 64-row block,
//   phase0: agg[64][256] = spmm rows (gather from Xg) -> Ag in LDS (swizzled)
//   phase1: agg' = relu(agg @ W1t + b1)   [A from Ag, in-place overwrite after barrier]
//   phase2: out  = act([Xg_rows | agg'] @ W2t + b2)  [64 x N2, K=512]
// BK=64, single-buffered Bs/As (round-10 proven staging), Ag layout = verified
// rounds 8-10 path (8-slot swizzle per 64-k window).
// LDS: As 8KB + Bs 32KB + Ag 32KB = 72.5KB -> 2 blocks/CU. Gather blocks (L3-bound)
// overlap GEMM blocks (MFMA-bound) on each CU.
// !NORM: relu + bf16 out.  NORM: row-L2 normalize + fp32 out.
template<int N2, bool NORM>
__global__ __launch_bounds__(256) void mega_kernel(
    const u16* __restrict__ Xg, const int* __restrict__ rp,
    const int* __restrict__ cols, const float* __restrict__ vals,
    const u16* __restrict__ W1t, const float* __restrict__ b1,
    const u16* __restrict__ W2t, const float* __restrict__ b2,
    void* __restrict__ outp, int M) {
  constexpr int NI2 = N2 / 32;          // B fragments per wave in phase 2
  __shared__ u16 As[64 * 64];
  __shared__ u16 Bs[256 * 64];
  __shared__ u16 Ag[64 * 256];
  __shared__ float red[64][2];

  const int tid = threadIdx.x;
  const int lane = tid & 63;
  const int wid = tid >> 6;
  const int wr = wid >> 1, wc = wid & 1;
  const int row0b = blockIdx.x * 64;
  const int lr = lane & 15, kg = lane >> 4;

  // ---------------- phase 0: gather this block's 64 agg rows into Ag ----------------
  {
    const u16* xp = Xg + (size_t)lane * 4;
    const int c = lane * 4;
    const int agoff = (c >> 6) * 64 + (c & 7);   // row-dependent part added below
    for (int t = 0; t < 16; ++t) {
      const int rl = wid * 16 + t;
      const int node = row0b + rl;
      if (node >= M) break;
      int e0 = rp[node], e1 = rp[node + 1];
      f32x4 s0 = {0.f, 0.f, 0.f, 0.f}, s1 = s0, s2 = s0, s3 = s0;
      int e = e0;
      for (; e + 8 <= e1; e += 8) {
        int cc[8]; float v[8]; u16x4 xv[8];
        #pragma unroll
        for (int i = 0; i < 8; ++i) { cc[i] = cols[e + i]; v[i] = vals[e + i]; }
        #pragma unroll
        for (int i = 0; i < 8; ++i) xv[i] = *(const u16x4*)(xp + (size_t)cc[i] * 256);
        s0 += v[0] * cvt4(xv[0]); s1 += v[1] * cvt4(xv[1]);
        s2 += v[2] * cvt4(xv[2]); s3 += v[3] * cvt4(xv[3]);
        s0 += v[4] * cvt4(xv[4]); s1 += v[5] * cvt4(xv[5]);
        s2 += v[6] * cvt4(xv[6]); s3 += v[7] * cvt4(xv[7]);
      }
      if (e + 4 <= e1) {
        int c0 = cols[e], c1 = cols[e + 1], c2 = cols[e + 2], c3 = cols[e + 3];
        float v0 = vals[e], v1 = vals[e + 1], v2 = vals[e + 2], v3 = vals[e + 3];
        s0 += v0 * cvt4(*(const u16x4*)(xp + (size_t)c0 * 256));
        s1 += v1 * cvt4(*(const u16x4*)(xp + (size_t)c1 * 256));
        s2 += v2 * cvt4(*(const u16x4*)(xp + (size_t)c2 * 256));
        s3 += v3 * cvt4(*(const u16x4*)(xp + (size_t)c3 * 256));
        e += 4;
      }
      for (; e < e1; ++e)
        s0 += vals[e] * cvt4(*(const u16x4*)(xp + (size_t)cols[e] * 256));
      f32x4 s = (s0 + s1) + (s2 + s3);
      u16x4 o = { f2bf(s.x), f2bf(s.y), f2bf(s.z), f2bf(s.w) };
      *(u16x4*)&Ag[rl * 256 + agoff + ((((c >> 3) & 7) ^ (rl & 7)) << 3)] = o;
    }
  }
  __syncthreads();  // Ag (agg) complete

  // A: 64 rows x 64 k of xh; 2 chunks per thread (round-6/10 pattern)
  auto stageA = [&](const u16* src, int kt) {
    #pragma unroll
    for (int i = 0; i < 2; ++i) {
      const int u = i * 256 + tid;
      const int row = u >> 3;
      const int kss = (u & 7) ^ (row & 7);
      int grow = row0b + row; if (grow >= M) grow = M - 1;
      gload_lds16(src + (size_t)grow * 256 + kt * 64 + kss * 8, &As[u * 8]);
    }
  };
  auto stageB = [&](const u16* Wt, int KW, int NC, int kt) {
    const int chunks = NC * 8;
    for (int i = 0; i < chunks / 256; ++i) {
      const int u = i * 256 + tid;
      const int col = u >> 3;
      const int kss = (u & 7) ^ (col & 7);
      gload_lds16(Wt + (size_t)col * KW + kt * 64 + kss * 8, &Bs[u * 8]);
    }
  };

  f32x4 acc[2][8];

  // ---------------- phase 1: agg' = relu(agg @ W1t + b1), A from Ag ----------------
  #pragma unroll
  for (int ni = 0; ni < 8; ++ni) {
    float bv = b1[wc * 128 + ni * 16 + lr];
    acc[0][ni] = (f32x4){bv, bv, bv, bv};
    acc[1][ni] = acc[0][ni];
  }
  for (int kt = 0; kt < 4; ++kt) {
    if (kt) __syncthreads();
    stageB(W1t, 256, 256, kt);
    __syncthreads();
    #pragma unroll
    for (int ks = 0; ks < 2; ++ks) {
      const int q = ks * 4 + kg;
      bf16x8 a[2], b[8];
      #pragma unroll
      for (int mi = 0; mi < 2; ++mi) {
        const int r = wr * 32 + mi * 16 + lr;
        a[mi] = __builtin_bit_cast(bf16x8,
            *(const u16x8*)&Ag[r * 256 + kt * 64 + ((q ^ (r & 7)) << 3)]);
      }
      #pragma unroll
      for (int ni = 0; ni < 8; ++ni) {
        const int cb = wc * 128 + ni * 16 + lr;
        b[ni] = __builtin_bit_cast(bf16x8,
            *(const u16x8*)&Bs[cb * 64 + ((q ^ (cb & 7)) << 3)]);
      }
      #pragma unroll
      for (int mi = 0; mi < 2; ++mi)
        #pragma unroll
        for (int ni = 0; ni < 8; ++ni)
          acc[mi][ni] = __builtin_amdgcn_mfma_f32_16x16x32_bf16(a[mi], b[ni], acc[mi][ni], 0, 0, 0);
    }
  }
  __syncthreads();  // all waves done reading Ag (agg) before in-place overwrite

  // relu + write agg' to Ag (verified 8-slot swizzle per 64-k window)
  #pragma unroll
  for (int mi = 0; mi < 2; ++mi)
    #pragma unroll
    for (int j = 0; j < 4; ++j) {
      const int rl = wr * 32 + mi * 16 + kg * 4 + j;
      #pragma unroll
      for (int ni = 0; ni < 8; ++ni) {
        float v = acc[mi][ni][j];
        v = v > 0.f ? v : 0.f;
        const int c = wc * 128 + ni * 16 + lr;
        Ag[rl * 256 + (c >> 6) * 64 + ((((c >> 3) & 7) ^ (rl & 7)) << 3) + (c & 7)] = f2bf(v);
      }
    }
  __syncthreads();  // Ag (agg') visible

  // ---------------- phase 2: out = act([xh | agg'] @ W2t + b2) ----------------
  #pragma unroll
  for (int ni = 0; ni < NI2; ++ni) {
    float bv = b2[wc * (N2 / 2) + ni * 16 + lr];
    acc[0][ni] = (f32x4){bv, bv, bv, bv};
    acc[1][ni] = acc[0][ni];
  }
  for (int kt = 0; kt < 8; ++kt) {
    if (kt) __syncthreads();
    stageB(W2t, 512, N2, kt);
    if (kt < 4) stageA(Xg, kt);
    __syncthreads();
    #pragma unroll
    for (int ks = 0; ks < 2; ++ks) {
      const int q = ks * 4 + kg;
      bf16x8 a[2], b[NI2];
      if (kt < 4) {
        #pragma unroll
        for (int mi = 0; mi < 2; ++mi) {
          const int r = wr * 32 + mi * 16 + lr;
          a[mi] = __builtin_bit_cast(bf16x8,
              *(const u16x8*)&As[r * 64 + ((q ^ (r & 7)) << 3)]);
        }
      } else {
        const int w = kt - 4;
        #pragma unroll
        for (int mi = 0; mi < 2; ++mi) {
          const int r = wr * 32 + mi * 16 + lr;
          a[mi] = __builtin_bit_cast(bf16x8,
              *(const u16x8*)&Ag[r * 256 + w * 64 + ((q ^ (r & 7)) << 3)]);
        }
      }
      #pragma unroll
      for (int ni = 0; ni < NI2; ++ni) {
        const int cb = wc * (N2 / 2) + ni * 16 + lr;
        b[ni] = __builtin_bit_cast(bf16x8,
            *(const u16x8*)&Bs[cb * 64 + ((q ^ (cb & 7)) << 3)]);
      }
      #pragma unroll
      for (int mi = 0; mi < 2; ++mi)
        #pragma unroll
        for (int ni = 0; ni < NI2; ++ni)
          acc[mi][ni] = __builtin_amdgcn_mfma_f32_16x16x32_bf16(a[mi], b[ni], acc[mi][ni], 0, 0, 0);
    }
  }

  // ---------------- epilogue ----------------
  float invn[2][4];
  if (NORM) {
    #pragma unroll
    for (int mi = 0; mi < 2; ++mi)
      #pragma unroll
      for (int j = 0; j < 4; ++j) {
        float p = 0.f;
        #pragma unroll
        for (int ni = 0; ni < NI2; ++ni) { float v = acc[mi][ni][j]; p += v * v; }
        #pragma unroll
        for (int m = 1; m < 16; m <<= 1) p += __shfl_xor(p, m, 64);
        int rl = wr * 32 + mi * 16 + kg * 4 + j;
        if (lr == 0) red[rl][wc] = p;
      }
    __syncthreads();
    #pragma unroll
    for (int mi = 0; mi < 2; ++mi)
      #pragma unroll
      for (int j = 0; j < 4; ++j) {
        int rl = wr * 32 + mi * 16 + kg * 4 + j;
        float ss = red[rl][0] + red[rl][1];
        float nrm = sqrtf(ss);
        nrm = nrm > 1e-12f ? nrm : 1e-12f;
        invn[mi][j] = 1.f / nrm;
      }
  }

  #pragma unroll
  for (int mi = 0; mi < 2; ++mi)
    #pragma unroll
    for (int j = 0; j < 4; ++j) {
      int r = row0b + wr * 32 + mi * 16 + kg * 4 + j;
      if (r >= M) continue;
      #pragma unroll
      for (int ni = 0; ni < NI2; ++ni) {
        float v = acc[mi][ni][j];
        int c = wc * (N2 / 2) + ni * 16 + lr;
        if (NORM) {
          ((float*)outp)[(size_t)r * N2 + c] = v * invn[mi][j];
        } else {
          v = v > 0.f ? v : 0.f;
          ((u16*)outp)[(size_t)r * N2 + c] = f2bf(v);
        }
      }
    }
}

extern "C" void kernel_launch(void* const* d_in, const int* in_sizes, int n_in,
                              void* d_out, int out_size, void* d_ws, size_t ws_size,
                              hipStream_t stream) {
  const float* x        = (const float*)d_in[0];
  const int*   adj_rows = (const int*)d_in[1];
  const int*   adj_cols = (const int*)d_in[2];
  const float* adj_vals = (const float*)d_in[3];
  const float* Wa0 = (const float*)d_in[4];
  const float* ba0 = (const float*)d_in[5];
  const float* Wa1 = (const float*)d_in[6];
  const float* ba1 = (const float*)d_in[7];
  const float* Wl0 = (const float*)d_in[8];
  const float* bl0 = (const float*)d_in[9];
  const float* Wl1 = (const float*)d_in[10];
  const float* bl1 = (const float*)d_in[11];

  const int nN = in_sizes[0] / 256;
  const int nE = in_sizes[1];

  char* ws = (char*)d_ws;
  size_t off = 0;
  auto alloc = [&](size_t bytes) -> void* {
    void* p = ws + off;
    off += (bytes + 255) & ~(size_t)255;
    return p;
  };
  u16* x_bf  = (u16*)alloc((size_t)nN * 256 * 2);
  u16* h_bf  = (u16*)alloc((size_t)nN * 256 * 2);
  int* rp    = (int*)alloc((size_t)(nN + 1) * 4);
  u16* wt_a0 = (u16*)alloc(256 * 256 * 2);
  u16* wt_a1 = (u16*)alloc(256 * 256 * 2);
  u16* wt_l0 = (u16*)alloc(512 * 256 * 2);
  u16* wt_l1 = (u16*)alloc(512 * 128 * 2);
  if (off > ws_size) return;

  dim3 blk(256);
  const int cvtxBlocks = (nN * 64 + 255) / 256;
  const int rpBlocks = (nN + 1 + 255) / 256;
  prep_kernel<<<dim3(cvtxBlocks + 1280 + rpBlocks), blk, 0, stream>>>(
      x, x_bf, cvtxBlocks, Wa0, wt_a0, Wa1, wt_a1, Wl0, wt_l0, Wl1, wt_l1,
      adj_rows, nE, rp, nN);

  const int MB = (nN + 63) / 64;
  dim3 gF(MB);

  // layer 0: spmm + linear0 fused
  mega_kernel<256, false><<<gF, blk, 0, stream>>>(
      x_bf, rp, adj_cols, adj_vals, wt_a0, ba0, wt_l0, bl0, h_bf, nN);
  // layer 1: spmm + linear1 + L2 normalize -> d_out (fp32)
  mega_kernel<128, true><<<gF, blk, 0, stream>>>(
      h_bf, rp, adj_cols, adj_vals, wt_a1, ba1, wt_l1, bl1, (float*)d_out, nN);
}

// Round 13
// 212.539 us; speedup vs baseline: 1.3711x; 1.3711x over previous
//
#include <hip/hip_runtime.h>

typedef unsigned short u16;
typedef __attribute__((ext_vector_type(8))) __bf16 bf16x8;
typedef __attribute__((ext_vector_type(4))) float f32x4;
typedef __attribute__((ext_vector_type(8))) u16 u16x8;
typedef __attribute__((ext_vector_type(4))) u16 u16x4;

__device__ __forceinline__ float bf2f(u16 u) {
  return __builtin_bit_cast(float, ((unsigned)u) << 16);
}
__device__ __forceinline__ u16 f2bf(float f) {
  unsigned x = __builtin_bit_cast(unsigned, f);
  x += 0x7fffu + ((x >> 16) & 1u);
  return (u16)(x >> 16);
}
__device__ __forceinline__ f32x4 cvt4(u16x4 v) {
  return (f32x4){bf2f(v.x), bf2f(v.y), bf2f(v.z), bf2f(v.w)};
}
__device__ __forceinline__ void gload_lds16(const void* g, void* l) {
  __builtin_amdgcn_global_load_lds(
      (const __attribute__((address_space(1))) void*)g,
      (__attribute__((address_space(3))) void*)l, 16, 0, 0);
}

// ---- fused prep: cvtx (x->bf16) | prepw x4 (W->Wt bf16) | rowptr, by block range ----
__global__ void prep_kernel(const float* __restrict__ x, u16* __restrict__ x_bf, int cvtxBlocks,
                            const float* __restrict__ W0, u16* __restrict__ T0,
                            const float* __restrict__ W1, u16* __restrict__ T1,
                            const float* __restrict__ W2, u16* __restrict__ T2,
                            const float* __restrict__ W3, u16* __restrict__ T3,
                            const int* __restrict__ rows, int nE, int* __restrict__ rp, int nN) {
  int b = blockIdx.x;
  if (b < cvtxBlocks) {
    int i = b * 256 + threadIdx.x;
    if (i >= nN * 64) return;
    const float4 v = ((const float4*)x)[i];
    u16x4 o = { f2bf(v.x), f2bf(v.y), f2bf(v.z), f2bf(v.w) };
    ((u16x4*)x_bf)[i] = o;
    return;
  }
  b -= cvtxBlocks;
  if (b < 1280) {
    int i = b * 256 + threadIdx.x;
    const float* W; u16* T; int K, N;
    if (i < 65536)        { W = W0; T = T0; K = 256; N = 256; }
    else if (i < 131072)  { W = W1; T = T1; K = 256; N = 256; i -= 65536; }
    else if (i < 262144)  { W = W2; T = T2; K = 512; N = 256; i -= 131072; }
    else if (i < 327680)  { W = W3; T = T3; K = 512; N = 128; i -= 262144; }
    else return;
    int k = i / N, n = i - k * N;
    T[(size_t)n * K + k] = f2bf(W[i]);
    return;
  }
  b -= 1280;
  int i = b * 256 + threadIdx.x;
  if (i > nN) return;
  int lo = 0, hi = nE;
  while (lo < hi) { int mid = (lo + hi) >> 1; if (rows[mid] < i) lo = mid + 1; else hi = mid; }
  rp[i] = lo;
}

// ---- spmm: out[i][:] = sum_e vals[e] * X[cols[e]][:]  (bf16 in/out, fp32 acc)
// 8-deep clean unroll, 4 chains, 8/4/1 tail cascade. 128-thread blocks (2 nodes).
// At its measured fetch-path floor (179 MB compulsory / ~3.65 TB/s).
__global__ __launch_bounds__(128) void spmm_kernel(
    const u16* __restrict__ X, const int* __restrict__ rp,
    const int* __restrict__ cols, const float* __restrict__ vals,
    u16* __restrict__ out, int nN) {
  int lane = threadIdx.x & 63;
  int node = blockIdx.x * 2 + (threadIdx.x >> 6);
  if (node >= nN) return;
  int e0 = rp[node], e1 = rp[node + 1];
  f32x4 s0 = {0.f, 0.f, 0.f, 0.f}, s1 = s0, s2 = s0, s3 = s0;
  const u16* xp = X + (size_t)lane * 4;
  int e = e0;
  for (; e + 8 <= e1; e += 8) {
    int c[8]; float v[8]; u16x4 xv[8];
    #pragma unroll
    for (int i = 0; i < 8; ++i) { c[i] = cols[e + i]; v[i] = vals[e + i]; }
    #pragma unroll
    for (int i = 0; i < 8; ++i) xv[i] = *(const u16x4*)(xp + (size_t)c[i] * 256);
    s0 += v[0] * cvt4(xv[0]); s1 += v[1] * cvt4(xv[1]);
    s2 += v[2] * cvt4(xv[2]); s3 += v[3] * cvt4(xv[3]);
    s0 += v[4] * cvt4(xv[4]); s1 += v[5] * cvt4(xv[5]);
    s2 += v[6] * cvt4(xv[6]); s3 += v[7] * cvt4(xv[7]);
  }
  if (e + 4 <= e1) {
    int c0 = cols[e], c1 = cols[e + 1], c2 = cols[e + 2], c3 = cols[e + 3];
    float v0 = vals[e], v1 = vals[e + 1], v2 = vals[e + 2], v3 = vals[e + 3];
    u16x4 x0 = *(const u16x4*)(xp + (size_t)c0 * 256);
    u16x4 x1 = *(const u16x4*)(xp + (size_t)c1 * 256);
    u16x4 x2 = *(const u16x4*)(xp + (size_t)c2 * 256);
    u16x4 x3 = *(const u16x4*)(xp + (size_t)c3 * 256);
    s0 += v0 * cvt4(x0); s1 += v1 * cvt4(x1);
    s2 += v2 * cvt4(x2); s3 += v3 * cvt4(x3);
    e += 4;
  }
  for (; e < e1; ++e) {
    int c = cols[e];
    float v = vals[e];
    s0 += v * cvt4(*(const u16x4*)(xp + (size_t)c * 256));
  }
  f32x4 s = (s0 + s1) + (s2 + s3);
  u16x4 o = { f2bf(s.x), f2bf(s.y), f2bf(s.z), f2bf(s.w) };
  *(u16x4*)(out + (size_t)node * 256 + lane * 4) = o;
}

// ---- fused layer kernel: per 64-row block,
//   phase1: agg' = relu(agg @ W1t + b1)   [64 x 256, K=256] -> Ag in LDS
//   phase2: out  = act([xh | agg'] @ W2t + b2)  [64 x N2, K=512]
// BK=32 (round-9 verified addressing) + double-buffer + SINGLE __syncthreads per
// step, prefetch issued BEFORE compute (rounds-3..7 proven flow): the compiler's
// pre-barrier vmcnt(0) lands after a full compute phase, hiding load latency.
// LDS: As 2x4KB + Bs 2x16KB + Ag 32KB = 72.5KB -> 2 blocks/CU (round-10 size).
// !NORM: relu + bf16 out.  NORM: row-L2 normalize + fp32 out.
template<int N2, bool NORM>
__global__ __launch_bounds__(256) void fused_kernel(
    const u16* __restrict__ agg, const u16* __restrict__ xh,
    const u16* __restrict__ W1t, const float* __restrict__ b1,
    const u16* __restrict__ W2t, const float* __restrict__ b2,
    void* __restrict__ outp, int M) {
  constexpr int NI2 = N2 / 32;          // B fragments per wave (phase 2)
  __shared__ u16 As[2][64 * 32];
  __shared__ u16 Bs[2][256 * 32];
  __shared__ u16 Ag[64 * 256];
  __shared__ float red[64][2];

  const int tid = threadIdx.x;
  const int lane = tid & 63;
  const int wid = tid >> 6;
  const int wr = wid >> 1, wc = wid & 1;
  const int row0b = blockIdx.x * 64;
  const int lr = lane & 15, kg = lane >> 4;

  auto stageA = [&](const u16* src, int kt, int buf) {
    const int row = tid >> 2, ksd = tid & 3;
    const int kss = ksd ^ ((row >> 1) & 3);
    int grow = row0b + row; if (grow >= M) grow = M - 1;
    gload_lds16(src + (size_t)grow * 256 + kt * 32 + kss * 8, &As[buf][tid * 8]);
  };
  auto stageB = [&](const u16* Wt, int KW, int NC, int kt, int buf) {
    for (int i = 0; i < NC / 64; ++i) {
      const int u = i * 256 + tid;
      const int col = u >> 2, ksd = u & 3;
      const int kss = ksd ^ ((col >> 1) & 3);
      gload_lds16(Wt + (size_t)col * KW + kt * 32 + kss * 8, &Bs[buf][u * 8]);
    }
  };

  f32x4 acc[2][8];

  // ---------------- phase 1: agg' = relu(agg @ W1t + b1) ----------------
  #pragma unroll
  for (int ni = 0; ni < 8; ++ni) {
    float bv = b1[wc * 128 + ni * 16 + lr];
    acc[0][ni] = (f32x4){bv, bv, bv, bv};
    acc[1][ni] = acc[0][ni];
  }
  stageA(agg, 0, 0); stageB(W1t, 256, 256, 0, 0);
  __syncthreads();  // tile 0 ready
  for (int kt = 0; kt < 8; ++kt) {
    const int cur = kt & 1;
    if (kt < 7) { stageA(agg, kt + 1, cur ^ 1); stageB(W1t, 256, 256, kt + 1, cur ^ 1); }
    bf16x8 a[2], b[8];
    #pragma unroll
    for (int mi = 0; mi < 2; ++mi) {
      const int r = wr * 32 + mi * 16 + lr;
      a[mi] = __builtin_bit_cast(bf16x8,
          *(const u16x8*)&As[cur][r * 32 + ((kg ^ ((r >> 1) & 3)) << 3)]);
    }
    #pragma unroll
    for (int ni = 0; ni < 8; ++ni) {
      const int cb = wc * 128 + ni * 16 + lr;
      b[ni] = __builtin_bit_cast(bf16x8,
          *(const u16x8*)&Bs[cur][cb * 32 + ((kg ^ ((cb >> 1) & 3)) << 3)]);
    }
    #pragma unroll
    for (int mi = 0; mi < 2; ++mi)
      #pragma unroll
      for (int ni = 0; ni < 8; ++ni)
        acc[mi][ni] = __builtin_amdgcn_mfma_f32_16x16x32_bf16(a[mi], b[ni], acc[mi][ni], 0, 0, 0);
    __syncthreads();  // prefetch landed + all waves done with buf[cur]
  }
  // relu + write agg' to Ag (8-slot swizzle per 64-k window; rounds 8-10 verified)
  #pragma unroll
  for (int mi = 0; mi < 2; ++mi)
    #pragma unroll
    for (int j = 0; j < 4; ++j) {
      const int rl = wr * 32 + mi * 16 + kg * 4 + j;
      #pragma unroll
      for (int ni = 0; ni < 8; ++ni) {
        float v = acc[mi][ni][j];
        v = v > 0.f ? v : 0.f;
        const int c = wc * 128 + ni * 16 + lr;
        Ag[rl * 256 + (c >> 6) * 64 + ((((c >> 3) & 7) ^ (rl & 7)) << 3) + (c & 7)] = f2bf(v);
      }
    }
  __syncthreads();  // Ag visible

  // ---------------- phase 2: out = act([xh | agg'] @ W2t + b2) ----------------
  #pragma unroll
  for (int ni = 0; ni < NI2; ++ni) {
    float bv = b2[wc * (N2 / 2) + ni * 16 + lr];
    acc[0][ni] = (f32x4){bv, bv, bv, bv};
    acc[1][ni] = acc[0][ni];
  }
  stageB(W2t, 512, N2, 0, 0); stageA(xh, 0, 0);
  __syncthreads();  // tile 0 ready
  for (int kt = 0; kt < 16; ++kt) {
    const int cur = kt & 1;
    if (kt < 15) {
      stageB(W2t, 512, N2, kt + 1, cur ^ 1);
      if (kt + 1 < 8) stageA(xh, kt + 1, cur ^ 1);
    }
    bf16x8 a[2], b[NI2];
    if (kt < 8) {
      #pragma unroll
      for (int mi = 0; mi < 2; ++mi) {
        const int r = wr * 32 + mi * 16 + lr;
        a[mi] = __builtin_bit_cast(bf16x8,
            *(const u16x8*)&As[cur][r * 32 + ((kg ^ ((r >> 1) & 3)) << 3)]);
      }
    } else {
      const int w64 = (kt - 8) >> 1;
      const int q8 = ((kt - 8) & 1) * 4 + kg;
      #pragma unroll
      for (int mi = 0; mi < 2; ++mi) {
        const int r = wr * 32 + mi * 16 + lr;
        a[mi] = __builtin_bit_cast(bf16x8,
            *(const u16x8*)&Ag[r * 256 + w64 * 64 + ((q8 ^ (r & 7)) << 3)]);
      }
    }
    #pragma unroll
    for (int ni = 0; ni < NI2; ++ni) {
      const int cb = wc * (N2 / 2) + ni * 16 + lr;
      b[ni] = __builtin_bit_cast(bf16x8,
          *(const u16x8*)&Bs[cur][cb * 32 + ((kg ^ ((cb >> 1) & 3)) << 3)]);
    }
    #pragma unroll
    for (int mi = 0; mi < 2; ++mi)
      #pragma unroll
      for (int ni = 0; ni < NI2; ++ni)
        acc[mi][ni] = __builtin_amdgcn_mfma_f32_16x16x32_bf16(a[mi], b[ni], acc[mi][ni], 0, 0, 0);
    __syncthreads();
  }

  // ---------------- epilogue ----------------
  float invn[2][4];
  if (NORM) {
    #pragma unroll
    for (int mi = 0; mi < 2; ++mi)
      #pragma unroll
      for (int j = 0; j < 4; ++j) {
        float p = 0.f;
        #pragma unroll
        for (int ni = 0; ni < NI2; ++ni) { float v = acc[mi][ni][j]; p += v * v; }
        #pragma unroll
        for (int m = 1; m < 16; m <<= 1) p += __shfl_xor(p, m, 64);
        int rl = wr * 32 + mi * 16 + kg * 4 + j;
        if (lr == 0) red[rl][wc] = p;
      }
    __syncthreads();
    #pragma unroll
    for (int mi = 0; mi < 2; ++mi)
      #pragma unroll
      for (int j = 0; j < 4; ++j) {
        int rl = wr * 32 + mi * 16 + kg * 4 + j;
        float ss = red[rl][0] + red[rl][1];
        float nrm = sqrtf(ss);
        nrm = nrm > 1e-12f ? nrm : 1e-12f;
        invn[mi][j] = 1.f / nrm;
      }
  }

  #pragma unroll
  for (int mi = 0; mi < 2; ++mi)
    #pragma unroll
    for (int j = 0; j < 4; ++j) {
      int r = row0b + wr * 32 + mi * 16 + kg * 4 + j;
      if (r >= M) continue;
      #pragma unroll
      for (int ni = 0; ni < NI2; ++ni) {
        float v = acc[mi][ni][j];
        int c = wc * (N2 / 2) + ni * 16 + lr;
        if (NORM) {
          ((float*)outp)[(size_t)r * N2 + c] = v * invn[mi][j];
        } else {
          v = v > 0.f ? v : 0.f;
          ((u16*)outp)[(size_t)r * N2 + c] = f2bf(v);
        }
      }
    }
}

extern "C" void kernel_launch(void* const* d_in, const int* in_sizes, int n_in,
                              void* d_out, int out_size, void* d_ws, size_t ws_size,
                              hipStream_t stream) {
  const float* x        = (const float*)d_in[0];
  const int*   adj_rows = (const int*)d_in[1];
  const int*   adj_cols = (const int*)d_in[2];
  const float* adj_vals = (const float*)d_in[3];
  const float* Wa0 = (const float*)d_in[4];
  const float* ba0 = (const float*)d_in[5];
  const float* Wa1 = (const float*)d_in[6];
  const float* ba1 = (const float*)d_in[7];
  const float* Wl0 = (const float*)d_in[8];
  const float* bl0 = (const float*)d_in[9];
  const float* Wl1 = (const float*)d_in[10];
  const float* bl1 = (const float*)d_in[11];

  const int nN = in_sizes[0] / 256;
  const int nE = in_sizes[1];

  char* ws = (char*)d_ws;
  size_t off = 0;
  auto alloc = [&](size_t bytes) -> void* {
    void* p = ws + off;
    off += (bytes + 255) & ~(size_t)255;
    return p;
  };
  u16* x_bf  = (u16*)alloc((size_t)nN * 256 * 2);
  u16* aggA  = (u16*)alloc((size_t)nN * 256 * 2);
  u16* h_bf  = (u16*)alloc((size_t)nN * 256 * 2);
  int* rp    = (int*)alloc((size_t)(nN + 1) * 4);
  u16* wt_a0 = (u16*)alloc(256 * 256 * 2);
  u16* wt_a1 = (u16*)alloc(256 * 256 * 2);
  u16* wt_l0 = (u16*)alloc(512 * 256 * 2);
  u16* wt_l1 = (u16*)alloc(512 * 128 * 2);
  if (off > ws_size) return;

  dim3 blk(256);
  const int cvtxBlocks = (nN * 64 + 255) / 256;
  const int rpBlocks = (nN + 1 + 255) / 256;
  prep_kernel<<<dim3(cvtxBlocks + 1280 + rpBlocks), blk, 0, stream>>>(
      x, x_bf, cvtxBlocks, Wa0, wt_a0, Wa1, wt_a1, Wl0, wt_l0, Wl1, wt_l1,
      adj_rows, nE, rp, nN);

  const int MB = (nN + 63) / 64;
  dim3 gF(MB);
  dim3 gNode((nN + 1) / 2);
  dim3 sblk(128);

  // layer 0
  spmm_kernel<<<gNode, sblk, 0, stream>>>(x_bf, rp, adj_cols, adj_vals, aggA, nN);
  fused_kernel<256, false><<<gF, blk, 0, stream>>>(aggA, x_bf, wt_a0, ba0, wt_l0, bl0, h_bf, nN);
  // layer 1 (+ fused L2 normalize -> d_out fp32)
  spmm_kernel<<<gNode, sblk, 0, stream>>>(h_bf, rp, adj_cols, adj_vals, aggA, nN);
  fused_kernel<128, true><<<gF, blk, 0, stream>>>(aggA, h_bf, wt_a1, ba1, wt_l1, bl1, (float*)d_out, nN);
}

// Round 14
// 199.668 us; speedup vs baseline: 1.4595x; 1.0645x over previous
//
#include <hip/hip_runtime.h>

typedef unsigned short u16;
typedef __attribute__((ext_vector_type(8))) __bf16 bf16x8;
typedef __attribute__((ext_vector_type(4))) float f32x4;
typedef __attribute__((ext_vector_type(8))) u16 u16x8;
typedef __attribute__((ext_vector_type(4))) u16 u16x4;

__device__ __forceinline__ float bf2f(u16 u) {
  return __builtin_bit_cast(float, ((unsigned)u) << 16);
}
__device__ __forceinline__ u16 f2bf(float f) {
  unsigned x = __builtin_bit_cast(unsigned, f);
  x += 0x7fffu + ((x >> 16) & 1u);
  return (u16)(x >> 16);
}
__device__ __forceinline__ f32x4 cvt4(u16x4 v) {
  return (f32x4){bf2f(v.x), bf2f(v.y), bf2f(v.z), bf2f(v.w)};
}
__device__ __forceinline__ void gload_lds16(const void* g, void* l) {
  __builtin_amdgcn_global_load_lds(
      (const __attribute__((address_space(1))) void*)g,
      (__attribute__((address_space(3))) void*)l, 16, 0, 0);
}

// ---- fused prep: cvtx (x->bf16) | prepw x4 (W->Wt bf16) | rowptr, by block range ----
__global__ void prep_kernel(const float* __restrict__ x, u16* __restrict__ x_bf, int cvtxBlocks,
                            const float* __restrict__ W0, u16* __restrict__ T0,
                            const float* __restrict__ W1, u16* __restrict__ T1,
                            const float* __restrict__ W2, u16* __restrict__ T2,
                            const float* __restrict__ W3, u16* __restrict__ T3,
                            const int* __restrict__ rows, int nE, int* __restrict__ rp, int nN) {
  int b = blockIdx.x;
  if (b < cvtxBlocks) {
    int i = b * 256 + threadIdx.x;
    if (i >= nN * 64) return;
    const float4 v = ((const float4*)x)[i];
    u16x4 o = { f2bf(v.x), f2bf(v.y), f2bf(v.z), f2bf(v.w) };
    ((u16x4*)x_bf)[i] = o;
    return;
  }
  b -= cvtxBlocks;
  if (b < 1280) {
    int i = b * 256 + threadIdx.x;
    const float* W; u16* T; int K, N;
    if (i < 65536)        { W = W0; T = T0; K = 256; N = 256; }
    else if (i < 131072)  { W = W1; T = T1; K = 256; N = 256; i -= 65536; }
    else if (i < 262144)  { W = W2; T = T2; K = 512; N = 256; i -= 131072; }
    else if (i < 327680)  { W = W3; T = T3; K = 512; N = 128; i -= 262144; }
    else return;
    int k = i / N, n = i - k * N;
    T[(size_t)n * K + k] = f2bf(W[i]);
    return;
  }
  b -= 1280;
  int i = b * 256 + threadIdx.x;
  if (i > nN) return;
  int lo = 0, hi = nE;
  while (lo < hi) { int mid = (lo + hi) >> 1; if (rows[mid] < i) lo = mid + 1; else hi = mid; }
  rp[i] = lo;
}

// ---- spmm: out[i][:] = sum_e vals[e] * X[cols[e]][:]  (bf16 in/out, fp32 acc)
// 8-deep clean unroll, 4 chains, 8/4/1 tail cascade. 128-thread blocks (2 nodes).
// At its measured fetch-path floor (179 MB compulsory / ~3.65 TB/s).
__global__ __launch_bounds__(128) void spmm_kernel(
    const u16* __restrict__ X, const int* __restrict__ rp,
    const int* __restrict__ cols, const float* __restrict__ vals,
    u16* __restrict__ out, int nN) {
  int lane = threadIdx.x & 63;
  int node = blockIdx.x * 2 + (threadIdx.x >> 6);
  if (node >= nN) return;
  int e0 = rp[node], e1 = rp[node + 1];
  f32x4 s0 = {0.f, 0.f, 0.f, 0.f}, s1 = s0, s2 = s0, s3 = s0;
  const u16* xp = X + (size_t)lane * 4;
  int e = e0;
  for (; e + 8 <= e1; e += 8) {
    int c[8]; float v[8]; u16x4 xv[8];
    #pragma unroll
    for (int i = 0; i < 8; ++i) { c[i] = cols[e + i]; v[i] = vals[e + i]; }
    #pragma unroll
    for (int i = 0; i < 8; ++i) xv[i] = *(const u16x4*)(xp + (size_t)c[i] * 256);
    s0 += v[0] * cvt4(xv[0]); s1 += v[1] * cvt4(xv[1]);
    s2 += v[2] * cvt4(xv[2]); s3 += v[3] * cvt4(xv[3]);
    s0 += v[4] * cvt4(xv[4]); s1 += v[5] * cvt4(xv[5]);
    s2 += v[6] * cvt4(xv[6]); s3 += v[7] * cvt4(xv[7]);
  }
  if (e + 4 <= e1) {
    int c0 = cols[e], c1 = cols[e + 1], c2 = cols[e + 2], c3 = cols[e + 3];
    float v0 = vals[e], v1 = vals[e + 1], v2 = vals[e + 2], v3 = vals[e + 3];
    u16x4 x0 = *(const u16x4*)(xp + (size_t)c0 * 256);
    u16x4 x1 = *(const u16x4*)(xp + (size_t)c1 * 256);
    u16x4 x2 = *(const u16x4*)(xp + (size_t)c2 * 256);
    u16x4 x3 = *(const u16x4*)(xp + (size_t)c3 * 256);
    s0 += v0 * cvt4(x0); s1 += v1 * cvt4(x1);
    s2 += v2 * cvt4(x2); s3 += v3 * cvt4(x3);
    e += 4;
  }
  for (; e < e1; ++e) {
    int c = cols[e];
    float v = vals[e];
    s0 += v * cvt4(*(const u16x4*)(xp + (size_t)c * 256));
  }
  f32x4 s = (s0 + s1) + (s2 + s3);
  u16x4 o = { f2bf(s.x), f2bf(s.y), f2bf(s.z), f2bf(s.w) };
  *(u16x4*)(out + (size_t)node * 256 + lane * 4) = o;
}

// ---- fused layer kernel: per 64-row block,
//   phase1: agg' = relu(agg @ W1t + b1)   [64 x 256, K=256] -> Ag in LDS
//   phase2: out  = act([xh | agg'] @ W2t + b2)  [64 x N2, K=512]
// BK=64 (m97 ratio: 32 MFMA between barriers), single-buffered As+Bs.
// LDS: As 8KB + Bs 32KB + Ag 32KB = 72.5KB -> 2 blocks/CU.
// Swizzle: 8 slots/k-window, slot = kseg ^ (row&7) (round-6 verified BK=64 pattern).
// Ag layout identical to round-8/9 verified path.
// !NORM: relu + bf16 out.  NORM: row-L2 normalize + fp32 out.
template<int N2, bool NORM>
__global__ __launch_bounds__(256) void fused_kernel(
    const u16* __restrict__ agg, const u16* __restrict__ xh,
    const u16* __restrict__ W1t, const float* __restrict__ b1,
    const u16* __restrict__ W2t, const float* __restrict__ b2,
    void* __restrict__ outp, int M) {
  constexpr int NI2 = N2 / 32;          // B fragments per wave in phase 2
  __shared__ u16 As[64 * 64];
  __shared__ u16 Bs[256 * 64];
  __shared__ u16 Ag[64 * 256];
  __shared__ float red[64][2];

  const int tid = threadIdx.x;
  const int lane = tid & 63;
  const int wid = tid >> 6;
  const int wr = wid >> 1, wc = wid & 1;
  const int row0b = blockIdx.x * 64;
  const int lr = lane & 15, kg = lane >> 4;

  // A: 64 rows x 64 k = 512 chunks of 16B; 2 per thread (round-6 pattern)
  auto stageA = [&](const u16* src, int kt) {
    #pragma unroll
    for (int i = 0; i < 2; ++i) {
      const int u = i * 256 + tid;        // 0..511
      const int row = u >> 3;             // 0..63
      const int kss = (u & 7) ^ (row & 7);
      int grow = row0b + row; if (grow >= M) grow = M - 1;
      gload_lds16(src + (size_t)grow * 256 + kt * 64 + kss * 8, &As[u * 8]);
    }
  };
  // B: NC cols x 64 k; KW = row stride of Wt
  auto stageB = [&](const u16* Wt, int KW, int NC, int kt) {
    const int chunks = NC * 8;
    for (int i = 0; i < chunks / 256; ++i) {
      const int u = i * 256 + tid;
      const int col = u >> 3;
      const int kss = (u & 7) ^ (col & 7);
      gload_lds16(Wt + (size_t)col * KW + kt * 64 + kss * 8, &Bs[u * 8]);
    }
  };

  f32x4 acc[2][8];

  // ---------------- phase 1: agg' = relu(agg @ W1t + b1) ----------------
  #pragma unroll
  for (int ni = 0; ni < 8; ++ni) {
    float bv = b1[wc * 128 + ni * 16 + lr];
    acc[0][ni] = (f32x4){bv, bv, bv, bv};
    acc[1][ni] = acc[0][ni];
  }
  for (int kt = 0; kt < 4; ++kt) {
    if (kt) __syncthreads();
    stageB(W1t, 256, 256, kt);
    stageA(agg, kt);
    __syncthreads();
    #pragma unroll
    for (int ks = 0; ks < 2; ++ks) {
      const int q = ks * 4 + kg;
      bf16x8 a[2], b[8];
      #pragma unroll
      for (int mi = 0; mi < 2; ++mi) {
        const int r = wr * 32 + mi * 16 + lr;
        a[mi] = __builtin_bit_cast(bf16x8,
            *(const u16x8*)&As[r * 64 + ((q ^ (r & 7)) << 3)]);
      }
      #pragma unroll
      for (int ni = 0; ni < 8; ++ni) {
        const int cb = wc * 128 + ni * 16 + lr;
        b[ni] = __builtin_bit_cast(bf16x8,
            *(const u16x8*)&Bs[cb * 64 + ((q ^ (cb & 7)) << 3)]);
      }
      #pragma unroll
      for (int mi = 0; mi < 2; ++mi)
        #pragma unroll
        for (int ni = 0; ni < 8; ++ni)
          acc[mi][ni] = __builtin_amdgcn_mfma_f32_16x16x32_bf16(a[mi], b[ni], acc[mi][ni], 0, 0, 0);
    }
  }
  // relu + write agg' to Ag (8-slot swizzle per 64-k window; round-8/9 verified)
  #pragma unroll
  for (int mi = 0; mi < 2; ++mi)
    #pragma unroll
    for (int j = 0; j < 4; ++j) {
      const int rl = wr * 32 + mi * 16 + kg * 4 + j;
      #pragma unroll
      for (int ni = 0; ni < 8; ++ni) {
        float v = acc[mi][ni][j];
        v = v > 0.f ? v : 0.f;
        const int c = wc * 128 + ni * 16 + lr;
        Ag[rl * 256 + (c >> 6) * 64 + ((((c >> 3) & 7) ^ (rl & 7)) << 3) + (c & 7)] = f2bf(v);
      }
    }
  __syncthreads();  // Ag visible; phase-1 As/Bs reads done before overwrite

  // ---------------- phase 2: out = act([xh | agg'] @ W2t + b2) ----------------
  #pragma unroll
  for (int ni = 0; ni < NI2; ++ni) {
    float bv = b2[wc * (N2 / 2) + ni * 16 + lr];
    acc[0][ni] = (f32x4){bv, bv, bv, bv};
    acc[1][ni] = acc[0][ni];
  }
  for (int kt = 0; kt < 8; ++kt) {
    if (kt) __syncthreads();
    stageB(W2t, 512, N2, kt);
    if (kt < 4) stageA(xh, kt);
    __syncthreads();
    #pragma unroll
    for (int ks = 0; ks < 2; ++ks) {
      const int q = ks * 4 + kg;
      bf16x8 a[2], b[NI2];
      if (kt < 4) {
        #pragma unroll
        for (int mi = 0; mi < 2; ++mi) {
          const int r = wr * 32 + mi * 16 + lr;
          a[mi] = __builtin_bit_cast(bf16x8,
              *(const u16x8*)&As[r * 64 + ((q ^ (r & 7)) << 3)]);
        }
      } else {
        const int w = kt - 4;
        #pragma unroll
        for (int mi = 0; mi < 2; ++mi) {
          const int r = wr * 32 + mi * 16 + lr;
          a[mi] = __builtin_bit_cast(bf16x8,
              *(const u16x8*)&Ag[r * 256 + w * 64 + ((q ^ (r & 7)) << 3)]);
        }
      }
      #pragma unroll
      for (int ni = 0; ni < NI2; ++ni) {
        const int cb = wc * (N2 / 2) + ni * 16 + lr;
        b[ni] = __builtin_bit_cast(bf16x8,
            *(const u16x8*)&Bs[cb * 64 + ((q ^ (cb & 7)) << 3)]);
      }
      #pragma unroll
      for (int mi = 0; mi < 2; ++mi)
        #pragma unroll
        for (int ni = 0; ni < NI2; ++ni)
          acc[mi][ni] = __builtin_amdgcn_mfma_f32_16x16x32_bf16(a[mi], b[ni], acc[mi][ni], 0, 0, 0);
    }
  }

  // ---------------- epilogue ----------------
  float invn[2][4];
  if (NORM) {
    #pragma unroll
    for (int mi = 0; mi < 2; ++mi)
      #pragma unroll
      for (int j = 0; j < 4; ++j) {
        float p = 0.f;
        #pragma unroll
        for (int ni = 0; ni < NI2; ++ni) { float v = acc[mi][ni][j]; p += v * v; }
        #pragma unroll
        for (int m = 1; m < 16; m <<= 1) p += __shfl_xor(p, m, 64);
        int rl = wr * 32 + mi * 16 + kg * 4 + j;
        if (lr == 0) red[rl][wc] = p;
      }
    __syncthreads();
    #pragma unroll
    for (int mi = 0; mi < 2; ++mi)
      #pragma unroll
      for (int j = 0; j < 4; ++j) {
        int rl = wr * 32 + mi * 16 + kg * 4 + j;
        float ss = red[rl][0] + red[rl][1];
        float nrm = sqrtf(ss);
        nrm = nrm > 1e-12f ? nrm : 1e-12f;
        invn[mi][j] = 1.f / nrm;
      }
  }

  #pragma unroll
  for (int mi = 0; mi < 2; ++mi)
    #pragma unroll
    for (int j = 0; j < 4; ++j) {
      int r = row0b + wr * 32 + mi * 16 + kg * 4 + j;
      if (r >= M) continue;
      #pragma unroll
      for (int ni = 0; ni < NI2; ++ni) {
        float v = acc[mi][ni][j];
        int c = wc * (N2 / 2) + ni * 16 + lr;
        if (NORM) {
          ((float*)outp)[(size_t)r * N2 + c] = v * invn[mi][j];
        } else {
          v = v > 0.f ? v : 0.f;
          ((u16*)outp)[(size_t)r * N2 + c] = f2bf(v);
        }
      }
    }
}

extern "C" void kernel_launch(void* const* d_in, const int* in_sizes, int n_in,
                              void* d_out, int out_size, void* d_ws, size_t ws_size,
                              hipStream_t stream) {
  const float* x        = (const float*)d_in[0];
  const int*   adj_rows = (const int*)d_in[1];
  const int*   adj_cols = (const int*)d_in[2];
  const float* adj_vals = (const float*)d_in[3];
  const float* Wa0 = (const float*)d_in[4];
  const float* ba0 = (const float*)d_in[5];
  const float* Wa1 = (const float*)d_in[6];
  const float* ba1 = (const float*)d_in[7];
  const float* Wl0 = (const float*)d_in[8];
  const float* bl0 = (const float*)d_in[9];
  const float* Wl1 = (const float*)d_in[10];
  const float* bl1 = (const float*)d_in[11];

  const int nN = in_sizes[0] / 256;
  const int nE = in_sizes[1];

  char* ws = (char*)d_ws;
  size_t off = 0;
  auto alloc = [&](size_t bytes) -> void* {
    void* p = ws + off;
    off += (bytes + 255) & ~(size_t)255;
    return p;
  };
  u16* x_bf  = (u16*)alloc((size_t)nN * 256 * 2);
  u16* aggA  = (u16*)alloc((size_t)nN * 256 * 2);
  u16* h_bf  = (u16*)alloc((size_t)nN * 256 * 2);
  int* rp    = (int*)alloc((size_t)(nN + 1) * 4);
  u16* wt_a0 = (u16*)alloc(256 * 256 * 2);
  u16* wt_a1 = (u16*)alloc(256 * 256 * 2);
  u16* wt_l0 = (u16*)alloc(512 * 256 * 2);
  u16* wt_l1 = (u16*)alloc(512 * 128 * 2);
  if (off > ws_size) return;

  dim3 blk(256);
  const int cvtxBlocks = (nN * 64 + 255) / 256;
  const int rpBlocks = (nN + 1 + 255) / 256;
  prep_kernel<<<dim3(cvtxBlocks + 1280 + rpBlocks), blk, 0, stream>>>(
      x, x_bf, cvtxBlocks, Wa0, wt_a0, Wa1, wt_a1, Wl0, wt_l0, Wl1, wt_l1,
      adj_rows, nE, rp, nN);

  const int MB = (nN + 63) / 64;
  dim3 gF(MB);
  dim3 gNode((nN + 1) / 2);
  dim3 sblk(128);

  // layer 0
  spmm_kernel<<<gNode, sblk, 0, stream>>>(x_bf, rp, adj_cols, adj_vals, aggA, nN);
  fused_kernel<256, false><<<gF, blk, 0, stream>>>(aggA, x_bf, wt_a0, ba0, wt_l0, bl0, h_bf, nN);
  // layer 1 (+ fused L2 normalize -> d_out fp32)
  spmm_kernel<<<gNode, sblk, 0, stream>>>(h_bf, rp, adj_cols, adj_vals, aggA, nN);
  fused_kernel<128, true><<<gF, blk, 0, stream>>>(aggA, h_bf, wt_a1, ba1, wt_l1, bl1, (float*)d_out, nN);
}